// Round 13
// baseline (1797.353 us; speedup 1.0000x reference)
//
#include <hip/hip_runtime.h>

#define EPS 1e-5f

// ---------------------------------------------------------------------------
// fill with constant
// ---------------------------------------------------------------------------
__global__ void fill_kernel(float* __restrict__ out, int n, float v) {
    int i = blockIdx.x * blockDim.x + threadIdx.x;
    if (i < n) out[i] = v;
}

__global__ void zero8_kernel(float* __restrict__ a) {
    if (threadIdx.x < 8) a[threadIdx.x] = 0.f;
}

// ---------------------------------------------------------------------------
// finalize for split-conv: buf = silu(buf + bias[oc]) in place (or no silu)
// n = co*plane (1048576 at every stage), ocShift = log2(plane)
// ---------------------------------------------------------------------------
__global__ void finalize_kernel(float* __restrict__ buf, long long batchStride,
                                int n, int ocShift, const float* __restrict__ bias,
                                int doSilu)
{
    int idx = blockIdx.x * blockDim.x + threadIdx.x;
    if (idx >= n) return;
    float* p = buf + (long long)blockIdx.y * batchStride;
    int oc = idx >> ocShift;
    float v = p[idx] + bias[oc];
    if (doSilu) v = v / (1.f + __expf(-v));
    p[idx] = v;
}

// ---------------------------------------------------------------------------
// GroupNorm(1) reduction: sum & sumsq over the (c, h, w) crop -> accs[2*batch]
// ---------------------------------------------------------------------------
__global__ void gn_reduce_kernel(const float* __restrict__ in, long long inBatchStride,
                                 int inPitch, long long inPlane, int useOrig,
                                 int c, int shift, const int* __restrict__ bboxes,
                                 int batch0, float* __restrict__ accs)
{
    int batch = batch0 + blockIdx.z;
    const int* bb = bboxes + 4 * batch;
    int l = bb[0], t = bb[1], r = bb[2], btm = bb[3];
    int h = (btm - t) << shift;
    int w = (r   - l) << shift;
    int oy = useOrig ? t : 0;   // only used at stage 0 (shift==0)
    int ox = useOrig ? l : 0;
    const float* base = in + (long long)blockIdx.z * inBatchStride;

    float s = 0.f, s2 = 0.f;
    int stride = gridDim.x * blockDim.x;

    if (((w | ox | inPitch) & 3) == 0) {
        // vectorized: every row segment is 16B aligned
        int w4 = w >> 2;
        int count4 = c * h * w4;
        for (int idx = blockIdx.x * blockDim.x + threadIdx.x; idx < count4; idx += stride) {
            int xw   = idx % w4;
            int rest = idx / w4;
            int y    = rest % h;
            int ch   = rest / h;
            const float4 v = *reinterpret_cast<const float4*>(
                base + (long long)ch * inPlane + (long long)(y + oy) * inPitch + (ox + 4 * xw));
            s  += (v.x + v.y) + (v.z + v.w);
            s2 += (v.x * v.x + v.y * v.y) + (v.z * v.z + v.w * v.w);
        }
    } else {
        int count = c * h * w;
        for (int idx = blockIdx.x * blockDim.x + threadIdx.x; idx < count; idx += stride) {
            int xw   = idx % w;
            int rest = idx / w;
            int y    = rest % h;
            int ch   = rest / h;
            float v = base[(long long)ch * inPlane + (long long)(y + oy) * inPitch + (xw + ox)];
            s  += v;
            s2 += v * v;
        }
    }

    // wave64 reduction
    for (int off = 32; off > 0; off >>= 1) {
        s  += __shfl_down(s, off);
        s2 += __shfl_down(s2, off);
    }
    // block reduction (4 waves) -> single atomic pair
    __shared__ float red[2][4];
    int wid = threadIdx.x >> 6;
    if ((threadIdx.x & 63) == 0) { red[0][wid] = s; red[1][wid] = s2; }
    __syncthreads();
    if (threadIdx.x == 0) {
        float ts = (red[0][0] + red[0][1]) + (red[0][2] + red[0][3]);
        float t2 = (red[1][0] + red[1][1]) + (red[1][2] + red[1][3]);
        atomicAdd(&accs[2 * batch],     ts);
        atomicAdd(&accs[2 * batch + 1], t2);
    }
}

// ---------------------------------------------------------------------------
// normalize (affine folded) + bicubic 2x (both axes, 16 taps) + add em crop
// writes bufB (c, 2h, 2w) with pitch outPitch
// ---------------------------------------------------------------------------
__global__ void normup_kernel(const float* __restrict__ in, long long inBatchStride,
                              int inPitch, long long inPlane, int useOrig,
                              const float* __restrict__ em, long long emBatchStride, int emPitch,
                              const float* __restrict__ gw, const float* __restrict__ gb,
                              const float* __restrict__ accs,
                              float* __restrict__ outB, long long outBatchStride, int outPitch,
                              int c, int shift, const int* __restrict__ bboxes,
                              int batch0, int tilesY)
{
    int batch = batch0 + blockIdx.z;
    const int* bb = bboxes + 4 * batch;
    int l = bb[0], t = bb[1], r = bb[2], btm = bb[3];
    int h = (btm - t) << shift;
    int w = (r   - l) << shift;
    int H2 = 2 * h, W2 = 2 * w;

    int ch = blockIdx.y / tilesY;
    int ty = blockIdx.y % tilesY;
    int y2 = ty * 16 + threadIdx.y;
    int x2 = blockIdx.x * 16 + threadIdx.x;
    if (y2 >= H2 || x2 >= W2) return;

    float count = (float)(c * h * w);
    float m  = accs[2 * batch] / count;
    float var = accs[2 * batch + 1] / count - m * m;
    float rs = rsqrtf(fmaxf(var, 0.f) + EPS);
    float alpha = rs * gw[ch];
    float beta  = gb[ch] - m * alpha;

    int oy = useOrig ? t : 0;
    int ox = useOrig ? l : 0;
    const float* base = in + (long long)blockIdx.z * inBatchStride + (long long)ch * inPlane;

    const float Wv[2][4] = {
        {-0.03515625f, 0.26171875f, 0.87890625f, -0.10546875f},   // even (W75)
        {-0.10546875f, 0.87890625f, 0.26171875f, -0.03515625f}};  // odd  (W25)

    int iy = y2 >> 1, py = y2 & 1;
    int ix = x2 >> 1, px = x2 & 1;
    int by = iy - 2 + py;
    int bx = ix - 2 + px;

    float acc = 0.f;
    #pragma unroll
    for (int a = 0; a < 4; a++) {
        int ry = by + a;
        ry = ry < 0 ? 0 : (ry > h - 1 ? h - 1 : ry);
        const float* rowp = base + (long long)(ry + oy) * inPitch + ox;
        float rsum = 0.f;
        #pragma unroll
        for (int q = 0; q < 4; q++) {
            int rx = bx + q;
            rx = rx < 0 ? 0 : (rx > w - 1 ? w - 1 : rx);
            rsum += Wv[px][q] * rowp[rx];
        }
        acc += Wv[py][a] * rsum;
    }

    float val = alpha * acc + beta;
    int S = 2 << shift;  // 2^(j+1)
    val += em[(long long)blockIdx.z * emBatchStride + (long long)ch * emPitch * emPitch
              + (long long)(t * S + y2) * emPitch + (l * S + x2)];

    outB[(long long)blockIdx.z * outBatchStride + (long long)ch * outPitch * outPitch
         + (long long)y2 * outPitch + x2] = val;
}

// ---------------------------------------------------------------------------
// conv3x3 (zero pad) + bias (+ silu).
// Block = 16x16 threads, each owning a 2x2 output patch -> 32x32 tile.
// Input staged in LDS in CICH-plane chunks (34x34 halo, row stride 36);
// weights staged in LDS, broadcast reads amortized 12:1 over FMAs (R12:
// 1701->768 us). R12 counters showed the residual limiter is GRID
// STARVATION: 32x32 tiles -> ~336 active blocks for 256 CUs -> 12.2%
// occupancy, staging latency exposed (VALUBusy 26.7%). Fix: cin-split.
// Each block handles ciPer channels starting at sp*ciPer (sp = split id
// from blockIdx.z high bits). doFinal=1: apply bias(+silu)/store (old
// path). doFinal=0: atomicAdd partial sums into pre-zeroed accumulator;
// bias+silu applied by finalize_kernel.
// ---------------------------------------------------------------------------
#define CICH 4

template<int COT>
__global__ void __launch_bounds__(256)
conv_reg_kernel(const float* __restrict__ inB, long long inBatchStride, int inPitch,
                const float* __restrict__ wts, const float* __restrict__ bias,
                int cin, int ciPer, int bShift, int doSilu,
                float* __restrict__ out, long long outBatchStride, int outPitch,
                int toMask, int doFinal, int shift, const int* __restrict__ bboxes,
                int batch0, int tilesY)
{
    int zb = blockIdx.z & ((1 << bShift) - 1);   // batch slot
    int sp = blockIdx.z >> bShift;               // cin-split index
    int batch = batch0 + zb;
    const int* bb = bboxes + 4 * batch;
    int l = bb[0], t = bb[1], r = bb[2], btm = bb[3];
    int h = (btm - t) << shift;
    int w = (r   - l) << shift;
    int H2 = 2 * h, W2 = 2 * w;

    int og = blockIdx.y / tilesY;
    int ty = blockIdx.y % tilesY;
    int oc0 = og * COT;
    int y0 = ty * 32;
    int x0 = blockIdx.x * 32;
    if (y0 >= H2 || x0 >= W2) return;  // uniform over block

    int ly = threadIdx.y, lx = threadIdx.x;
    int tid = ly * 16 + lx;
    int py0 = y0 + 2 * ly;   // this thread's 2x2 output base
    int px0 = x0 + 2 * lx;

    // 34x34 halo tile, row stride 36 (keeps float2 reads 8B-aligned)
    __shared__ float tile[CICH][34][36];
    // per-chunk weights; slot padded to 12 floats -> two aligned float4 + one
    __shared__ __align__(16) float wsh[COT][CICH][12];

    const float* base = inB + (long long)zb * inBatchStride;
    long long plane = (long long)inPitch * inPitch;
    long long oplane = (long long)outPitch * outPitch;

    float acc[COT][2][2];
    #pragma unroll
    for (int o = 0; o < COT; o++)
        #pragma unroll
        for (int rr = 0; rr < 2; rr++)
            #pragma unroll
            for (int ss = 0; ss < 2; ss++) acc[o][rr][ss] = 0.f;

    int ciStart = sp * ciPer;
    int ciEnd = ciStart + ciPer;
    for (int ci0 = ciStart; ci0 < ciEnd; ci0 += CICH) {
        // stage CICH input planes (34x34 halo each) into LDS
        for (int q = tid; q < CICH * 1156; q += 256) {
            int p   = q / 1156;
            int rem = q - p * 1156;
            int yy  = rem / 34;
            int xx  = rem - yy * 34;
            int gy = y0 - 1 + yy, gx = x0 - 1 + xx;
            float v = (gy >= 0 && gy < H2 && gx >= 0 && gx < W2)
                          ? base[(long long)(ci0 + p) * plane + (long long)gy * inPitch + gx]
                          : 0.f;
            tile[p][yy][xx] = v;
        }
        // stage this chunk's weights (COT*CICH*9 <= 288 floats, coalesced)
        for (int q = tid; q < COT * CICH * 9; q += 256) {
            int o   = q / (CICH * 9);
            int rem = q - o * (CICH * 9);
            int p   = rem / 9;
            int k   = rem - p * 9;
            wsh[o][p][k] = wts[((long long)(oc0 + o) * cin + (ci0 + p)) * 9 + k];
        }
        __syncthreads();

        #pragma unroll
        for (int p = 0; p < CICH; p++) {
            // 4x4 input patch for this thread's 2x2 outputs (8x ds_read_b64)
            float v[4][4];
            #pragma unroll
            for (int rr = 0; rr < 4; rr++) {
                const float2 a = *reinterpret_cast<const float2*>(&tile[p][2 * ly + rr][2 * lx]);
                const float2 b = *reinterpret_cast<const float2*>(&tile[p][2 * ly + rr][2 * lx + 2]);
                v[rr][0] = a.x; v[rr][1] = a.y; v[rr][2] = b.x; v[rr][3] = b.y;
            }
            #pragma unroll
            for (int o = 0; o < COT; o++) {
                const float4 wA = *reinterpret_cast<const float4*>(&wsh[o][p][0]);
                const float4 wB = *reinterpret_cast<const float4*>(&wsh[o][p][4]);
                const float  w8 = wsh[o][p][8];
                #pragma unroll
                for (int rr = 0; rr < 2; rr++) {
                    #pragma unroll
                    for (int ss = 0; ss < 2; ss++) {
                        acc[o][rr][ss] += wA.x * v[rr    ][ss] + wA.y * v[rr    ][ss + 1] + wA.z * v[rr    ][ss + 2]
                                        + wA.w * v[rr + 1][ss] + wB.x * v[rr + 1][ss + 1] + wB.y * v[rr + 1][ss + 2]
                                        + wB.z * v[rr + 2][ss] + wB.w * v[rr + 2][ss + 1] + w8   * v[rr + 2][ss + 2];
                    }
                }
            }
        }
        __syncthreads();
    }

    if (doFinal) {
        #pragma unroll
        for (int o = 0; o < COT; o++) {
            float b = bias[oc0 + o];
            #pragma unroll
            for (int rr = 0; rr < 2; rr++) {
                #pragma unroll
                for (int ss = 0; ss < 2; ss++) {
                    int oy2 = py0 + rr, ox2 = px0 + ss;
                    if (oy2 >= H2 || ox2 >= W2) continue;
                    float v = acc[o][rr][ss] + b;
                    if (doSilu) v = v / (1.f + __expf(-v));
                    if (toMask) {
                        int S = 2 << shift;   // 16 at stage 3
                        out[(long long)batch * 1024 * 1024 + (long long)(t * S + oy2) * 1024 + (l * S + ox2)] = v;
                    } else {
                        out[(long long)zb * outBatchStride + (long long)(oc0 + o) * oplane
                            + (long long)oy2 * outPitch + ox2] = v;
                    }
                }
            }
        }
    } else {
        // partial sum -> accumulator (bias/silu deferred to finalize_kernel)
        #pragma unroll
        for (int o = 0; o < COT; o++) {
            #pragma unroll
            for (int rr = 0; rr < 2; rr++) {
                #pragma unroll
                for (int ss = 0; ss < 2; ss++) {
                    int oy2 = py0 + rr, ox2 = px0 + ss;
                    if (oy2 >= H2 || ox2 >= W2) continue;
                    atomicAdd(&out[(long long)zb * outBatchStride + (long long)(oc0 + o) * oplane
                                   + (long long)oy2 * outPitch + ox2], acc[o][rr][ss]);
                }
            }
        }
    }
}

// ---------------------------------------------------------------------------
static inline void launch_conv(int co, int tiles32, int nz, int S,
                               const float* inB, long long inBS, int inPitch,
                               const float* wts, const float* bias, int cin, int doSilu,
                               float* out, long long outBS, int outPitch,
                               int toMask, int shift, const int* bboxes, int batch0,
                               hipStream_t stream)
{
    dim3 blk(16, 16);
    int bShift = (nz == 4) ? 2 : 0;
    int ciPer = cin / S;
    int doFinal = (S == 1) ? 1 : 0;
    dim3 grid;
    if (co == 64)      grid = dim3(tiles32, tiles32 * 8, nz * S);   // 8 groups of 8
    else if (co == 16) grid = dim3(tiles32, tiles32 * 2, nz * S);   // 2 groups of 8
    else               grid = dim3(tiles32, tiles32,     nz * S);   // 1 group (4 or 1)

    if (co == 64 || co == 16) {
        conv_reg_kernel<8><<<grid, blk, 0, stream>>>(
            inB, inBS, inPitch, wts, bias, cin, ciPer, bShift, doSilu,
            out, outBS, outPitch, toMask, doFinal, shift, bboxes, batch0, tiles32);
    } else if (co == 4) {
        conv_reg_kernel<4><<<grid, blk, 0, stream>>>(
            inB, inBS, inPitch, wts, bias, cin, ciPer, bShift, doSilu,
            out, outBS, outPitch, toMask, doFinal, shift, bboxes, batch0, tiles32);
    } else {
        conv_reg_kernel<1><<<grid, blk, 0, stream>>>(
            inB, inBS, inPitch, wts, bias, cin, ciPer, bShift, doSilu,
            out, outBS, outPitch, toMask, doFinal, shift, bboxes, batch0, tiles32);
    }
}

extern "C" void kernel_launch(void* const* d_in, const int* in_sizes, int n_in,
                              void* d_out, int out_size, void* d_ws, size_t ws_size,
                              hipStream_t stream)
{
    const float* x  = (const float*)d_in[0];
    const float* em[4];
    const float* gw[4];
    const float* gb[4];
    const float* cw[4];
    const float* cb[4];
    for (int j = 0; j < 4; j++) {
        em[j] = (const float*)d_in[1 + j];
        gw[j] = (const float*)d_in[5 + 4 * j];
        gb[j] = (const float*)d_in[6 + 4 * j];
        cw[j] = (const float*)d_in[7 + 4 * j];
        cb[j] = (const float*)d_in[8 + 4 * j];
    }
    const int* bboxes = (const int*)d_in[21];
    float* out = (float*)d_out;
    float* ws  = (float*)d_ws;

    const int chans[4] = {256, 64, 16, 4};
    const int couts[4] = {64, 16, 4, 1};
    const int splits[4] = {4, 4, 1, 1};     // cin-split factors (cin/S % 4 == 0)

    const long long A_OFF  = 256;
    const long long A_SLOT = 1048576;   // floats; co*up^2 == A_SLOT at every stage
    const long long B_SLOT = 4194304;   // floats: c_j * (128<<j)^2, same all stages

    bool par = ws_size >= (size_t)(A_OFF + 4 * A_SLOT + 4 * B_SLOT) * 4;
    int nA = par ? 4 : 1;
    float* accs = ws;
    float* bufA = ws + A_OFF;
    float* bufB = ws + A_OFF + nA * A_SLOT;

    // mask = -100 everywhere
    fill_kernel<<<(4194304 + 255) / 256, 256, 0, stream>>>(out, 4194304, -100.0f);

    if (par) {
        for (int j = 0; j < 4; j++) {
            int c = chans[j], co = couts[j], shift = j;
            int inPitch = 64 << j;
            long long inPlane = (long long)inPitch * inPitch;
            int upPitch = 128 << j;
            int tiles = upPitch / 16;
            int tiles32 = upPitch / 32;
            int E = 128 << j;
            long long emStride = (long long)c * E * E;
            int S = splits[j];

            const float* gin = (j == 0) ? x : bufA;
            long long ginStride = (j == 0) ? (long long)256 * 64 * 64 : A_SLOT;
            int useOrig = (j == 0) ? 1 : 0;

            zero8_kernel<<<1, 64, 0, stream>>>(accs);
            gn_reduce_kernel<<<dim3(512, 1, 4), 256, 0, stream>>>(
                gin, ginStride, inPitch, inPlane, useOrig, c, shift, bboxes, 0, accs);
            normup_kernel<<<dim3(tiles, tiles * c, 4), dim3(16, 16), 0, stream>>>(
                gin, ginStride, inPitch, inPlane, useOrig,
                em[j], emStride, E, gw[j], gb[j], accs,
                bufB, B_SLOT, upPitch, c, shift, bboxes, 0, tiles);
            if (S > 1) {
                // zero accumulator (AFTER normup consumed bufA; stream-ordered)
                fill_kernel<<<(int)((4 * A_SLOT + 255) / 256), 256, 0, stream>>>(
                    bufA, (int)(4 * A_SLOT), 0.f);
            }
            launch_conv(co, tiles32, 4, S,
                        bufB, B_SLOT, upPitch, cw[j], cb[j], c, (j < 3) ? 1 : 0,
                        (j < 3) ? bufA : out, (j < 3) ? A_SLOT : 0, upPitch,
                        (j == 3) ? 1 : 0, shift, bboxes, 0, stream);
            if (S > 1) {
                int ocShift = 2 * (7 + j);   // log2(upPitch^2): 14 at j=0, 16 at j=1
                finalize_kernel<<<dim3(4096, 4), 256, 0, stream>>>(
                    bufA, A_SLOT, (int)A_SLOT, ocShift, cb[j], (j < 3) ? 1 : 0);
            }
        }
    } else {
        for (int i = 0; i < 4; i++) {
            for (int j = 0; j < 4; j++) {
                int c = chans[j], co = couts[j], shift = j;
                int inPitch = 64 << j;
                long long inPlane = (long long)inPitch * inPitch;
                int upPitch = 128 << j;
                int tiles = upPitch / 16;
                int tiles32 = upPitch / 32;
                int E = 128 << j;
                long long emStride = (long long)c * E * E;
                int S = splits[j];

                const float* gin = (j == 0) ? (x + (long long)i * 256 * 64 * 64) : bufA;
                int useOrig = (j == 0) ? 1 : 0;

                zero8_kernel<<<1, 64, 0, stream>>>(accs);
                gn_reduce_kernel<<<dim3(512, 1, 1), 256, 0, stream>>>(
                    gin, 0, inPitch, inPlane, useOrig, c, shift, bboxes, i, accs);
                normup_kernel<<<dim3(tiles, tiles * c, 1), dim3(16, 16), 0, stream>>>(
                    gin, 0, inPitch, inPlane, useOrig,
                    em[j] + (long long)i * emStride, 0, E, gw[j], gb[j], accs,
                    bufB, 0, upPitch, c, shift, bboxes, i, tiles);
                if (S > 1) {
                    fill_kernel<<<(int)((A_SLOT + 255) / 256), 256, 0, stream>>>(
                        bufA, (int)A_SLOT, 0.f);
                }
                launch_conv(co, tiles32, 1, S,
                            bufB, 0, upPitch, cw[j], cb[j], c, (j < 3) ? 1 : 0,
                            (j < 3) ? bufA : out, 0, upPitch,
                            (j == 3) ? 1 : 0, shift, bboxes, i, stream);
                if (S > 1) {
                    int ocShift = 2 * (7 + j);
                    finalize_kernel<<<dim3(4096, 1), 256, 0, stream>>>(
                        bufA, 0, (int)A_SLOT, ocShift, cb[j], (j < 3) ? 1 : 0);
                }
            }
        }
    }
}

// Round 14
// 1428.959 us; speedup vs baseline: 1.2578x; 1.2578x over previous
//
#include <hip/hip_runtime.h>

#define EPS 1e-5f

// ---------------------------------------------------------------------------
// fill with constant
// ---------------------------------------------------------------------------
__global__ void fill_kernel(float* __restrict__ out, int n, float v) {
    int i = blockIdx.x * blockDim.x + threadIdx.x;
    if (i < n) out[i] = v;
}

__global__ void zero8_kernel(float* __restrict__ a) {
    if (threadIdx.x < 8) a[threadIdx.x] = 0.f;
}

// ---------------------------------------------------------------------------
// finalize for split-conv: buf = silu(buf + bias[oc]) in place (or no silu)
// (kept for the cin-split path; unused when splits are all 1)
// ---------------------------------------------------------------------------
__global__ void finalize_kernel(float* __restrict__ buf, long long batchStride,
                                int n, int ocShift, const float* __restrict__ bias,
                                int doSilu)
{
    int idx = blockIdx.x * blockDim.x + threadIdx.x;
    if (idx >= n) return;
    float* p = buf + (long long)blockIdx.y * batchStride;
    int oc = idx >> ocShift;
    float v = p[idx] + bias[oc];
    if (doSilu) v = v / (1.f + __expf(-v));
    p[idx] = v;
}

// ---------------------------------------------------------------------------
// GroupNorm(1) reduction: sum & sumsq over the (c, h, w) crop -> accs[2*batch]
// ---------------------------------------------------------------------------
__global__ void gn_reduce_kernel(const float* __restrict__ in, long long inBatchStride,
                                 int inPitch, long long inPlane, int useOrig,
                                 int c, int shift, const int* __restrict__ bboxes,
                                 int batch0, float* __restrict__ accs)
{
    int batch = batch0 + blockIdx.z;
    const int* bb = bboxes + 4 * batch;
    int l = bb[0], t = bb[1], r = bb[2], btm = bb[3];
    int h = (btm - t) << shift;
    int w = (r   - l) << shift;
    int oy = useOrig ? t : 0;   // only used at stage 0 (shift==0)
    int ox = useOrig ? l : 0;
    const float* base = in + (long long)blockIdx.z * inBatchStride;

    float s = 0.f, s2 = 0.f;
    int stride = gridDim.x * blockDim.x;

    if (((w | ox | inPitch) & 3) == 0) {
        // vectorized: every row segment is 16B aligned
        int w4 = w >> 2;
        int count4 = c * h * w4;
        for (int idx = blockIdx.x * blockDim.x + threadIdx.x; idx < count4; idx += stride) {
            int xw   = idx % w4;
            int rest = idx / w4;
            int y    = rest % h;
            int ch   = rest / h;
            const float4 v = *reinterpret_cast<const float4*>(
                base + (long long)ch * inPlane + (long long)(y + oy) * inPitch + (ox + 4 * xw));
            s  += (v.x + v.y) + (v.z + v.w);
            s2 += (v.x * v.x + v.y * v.y) + (v.z * v.z + v.w * v.w);
        }
    } else {
        int count = c * h * w;
        for (int idx = blockIdx.x * blockDim.x + threadIdx.x; idx < count; idx += stride) {
            int xw   = idx % w;
            int rest = idx / w;
            int y    = rest % h;
            int ch   = rest / h;
            float v = base[(long long)ch * inPlane + (long long)(y + oy) * inPitch + (xw + ox)];
            s  += v;
            s2 += v * v;
        }
    }

    // wave64 reduction
    for (int off = 32; off > 0; off >>= 1) {
        s  += __shfl_down(s, off);
        s2 += __shfl_down(s2, off);
    }
    // block reduction (4 waves) -> single atomic pair
    __shared__ float red[2][4];
    int wid = threadIdx.x >> 6;
    if ((threadIdx.x & 63) == 0) { red[0][wid] = s; red[1][wid] = s2; }
    __syncthreads();
    if (threadIdx.x == 0) {
        float ts = (red[0][0] + red[0][1]) + (red[0][2] + red[0][3]);
        float t2 = (red[1][0] + red[1][1]) + (red[1][2] + red[1][3]);
        atomicAdd(&accs[2 * batch],     ts);
        atomicAdd(&accs[2 * batch + 1], t2);
    }
}

// ---------------------------------------------------------------------------
// normalize (affine folded) + bicubic 2x (both axes, 16 taps) + add em crop
// writes bufB (c, 2h, 2w) with pitch outPitch
// ---------------------------------------------------------------------------
__global__ void normup_kernel(const float* __restrict__ in, long long inBatchStride,
                              int inPitch, long long inPlane, int useOrig,
                              const float* __restrict__ em, long long emBatchStride, int emPitch,
                              const float* __restrict__ gw, const float* __restrict__ gb,
                              const float* __restrict__ accs,
                              float* __restrict__ outB, long long outBatchStride, int outPitch,
                              int c, int shift, const int* __restrict__ bboxes,
                              int batch0, int tilesY)
{
    int batch = batch0 + blockIdx.z;
    const int* bb = bboxes + 4 * batch;
    int l = bb[0], t = bb[1], r = bb[2], btm = bb[3];
    int h = (btm - t) << shift;
    int w = (r   - l) << shift;
    int H2 = 2 * h, W2 = 2 * w;

    int ch = blockIdx.y / tilesY;
    int ty = blockIdx.y % tilesY;
    int y2 = ty * 16 + threadIdx.y;
    int x2 = blockIdx.x * 16 + threadIdx.x;
    if (y2 >= H2 || x2 >= W2) return;

    float count = (float)(c * h * w);
    float m  = accs[2 * batch] / count;
    float var = accs[2 * batch + 1] / count - m * m;
    float rs = rsqrtf(fmaxf(var, 0.f) + EPS);
    float alpha = rs * gw[ch];
    float beta  = gb[ch] - m * alpha;

    int oy = useOrig ? t : 0;
    int ox = useOrig ? l : 0;
    const float* base = in + (long long)blockIdx.z * inBatchStride + (long long)ch * inPlane;

    const float Wv[2][4] = {
        {-0.03515625f, 0.26171875f, 0.87890625f, -0.10546875f},   // even (W75)
        {-0.10546875f, 0.87890625f, 0.26171875f, -0.03515625f}};  // odd  (W25)

    int iy = y2 >> 1, py = y2 & 1;
    int ix = x2 >> 1, px = x2 & 1;
    int by = iy - 2 + py;
    int bx = ix - 2 + px;

    float acc = 0.f;
    #pragma unroll
    for (int a = 0; a < 4; a++) {
        int ry = by + a;
        ry = ry < 0 ? 0 : (ry > h - 1 ? h - 1 : ry);
        const float* rowp = base + (long long)(ry + oy) * inPitch + ox;
        float rsum = 0.f;
        #pragma unroll
        for (int q = 0; q < 4; q++) {
            int rx = bx + q;
            rx = rx < 0 ? 0 : (rx > w - 1 ? w - 1 : rx);
            rsum += Wv[px][q] * rowp[rx];
        }
        acc += Wv[py][a] * rsum;
    }

    float val = alpha * acc + beta;
    int S = 2 << shift;  // 2^(j+1)
    val += em[(long long)blockIdx.z * emBatchStride + (long long)ch * emPitch * emPitch
              + (long long)(t * S + y2) * emPitch + (l * S + x2)];

    outB[(long long)blockIdx.z * outBatchStride + (long long)ch * outPitch * outPitch
         + (long long)y2 * outPitch + x2] = val;
}

// ---------------------------------------------------------------------------
// conv3x3 (zero pad) + bias (+ silu).
// Block = 16x16 threads, each owning a 2x2 output patch -> 32x32 tile.
// Input + weights staged in LDS per CICH-plane chunk; weight broadcast reads
// amortized 12:1 over FMAs (R12: 1701->768 us).
// R13 cycle accounting found the residual: the staging loop
// (runtime trip count, load->ds_write dependent per iteration) compiled to
// 19 SERIALIZED global round-trips per chunk (~16K of 21.7K cycles/chunk).
// Fix: two-phase staging. Phase A issues all 19 tile loads + weight loads
// into registers (fully unrolled, independent -> one latency exposure);
// phase B writes them to LDS. ~21 extra VGPRs.
// ---------------------------------------------------------------------------
#define CICH 4

template<int COT>
__global__ void __launch_bounds__(256)
conv_reg_kernel(const float* __restrict__ inB, long long inBatchStride, int inPitch,
                const float* __restrict__ wts, const float* __restrict__ bias,
                int cin, int ciPer, int bShift, int doSilu,
                float* __restrict__ out, long long outBatchStride, int outPitch,
                int toMask, int doFinal, int shift, const int* __restrict__ bboxes,
                int batch0, int tilesY)
{
    int zb = blockIdx.z & ((1 << bShift) - 1);   // batch slot
    int sp = blockIdx.z >> bShift;               // cin-split index (0 when S=1)
    int batch = batch0 + zb;
    const int* bb = bboxes + 4 * batch;
    int l = bb[0], t = bb[1], r = bb[2], btm = bb[3];
    int h = (btm - t) << shift;
    int w = (r   - l) << shift;
    int H2 = 2 * h, W2 = 2 * w;

    int og = blockIdx.y / tilesY;
    int ty = blockIdx.y % tilesY;
    int oc0 = og * COT;
    int y0 = ty * 32;
    int x0 = blockIdx.x * 32;
    if (y0 >= H2 || x0 >= W2) return;  // uniform over block

    int ly = threadIdx.y, lx = threadIdx.x;
    int tid = ly * 16 + lx;
    int py0 = y0 + 2 * ly;   // this thread's 2x2 output base
    int px0 = x0 + 2 * lx;

    // 34x34 halo tile, row stride 36 (keeps float2 reads 8B-aligned)
    __shared__ float tile[CICH][34][36];
    // per-chunk weights; slot padded to 12 floats -> two aligned float4 + one
    __shared__ __align__(16) float wsh[COT][CICH][12];

    const float* base = inB + (long long)zb * inBatchStride;
    long long plane = (long long)inPitch * inPitch;
    long long oplane = (long long)outPitch * outPitch;

    constexpr int TITEMS = CICH * 1156;             // 4624
    constexpr int NIT    = (TITEMS + 255) / 256;    // 19
    constexpr int WITEMS = COT * CICH * 9;
    constexpr int NWIT   = (WITEMS + 255) / 256;    // 2 (COT=8) or 1

    float acc[COT][2][2];
    #pragma unroll
    for (int o = 0; o < COT; o++)
        #pragma unroll
        for (int rr = 0; rr < 2; rr++)
            #pragma unroll
            for (int ss = 0; ss < 2; ss++) acc[o][rr][ss] = 0.f;

    int ciStart = sp * ciPer;
    int ciEnd = ciStart + ciPer;
    for (int ci0 = ciStart; ci0 < ciEnd; ci0 += CICH) {
        // ---- phase A: issue ALL global loads into registers (one latency) --
        float rbuf[NIT];
        #pragma unroll
        for (int it = 0; it < NIT; ++it) {
            int q = tid + it * 256;
            float v = 0.f;
            if (q < TITEMS) {
                int p   = q / 1156;
                int rem = q - p * 1156;
                int yy  = rem / 34;
                int xx  = rem - yy * 34;
                int gy = y0 - 1 + yy, gx = x0 - 1 + xx;
                if (gy >= 0 && gy < H2 && gx >= 0 && gx < W2)
                    v = base[(long long)(ci0 + p) * plane + (long long)gy * inPitch + gx];
            }
            rbuf[it] = v;
        }
        float wreg[NWIT];
        #pragma unroll
        for (int it = 0; it < NWIT; ++it) {
            int q = tid + it * 256;
            float v = 0.f;
            if (q < WITEMS) {
                int o   = q / (CICH * 9);
                int rem = q - o * (CICH * 9);
                int p   = rem / 9;
                int k   = rem - p * 9;
                v = wts[((long long)(oc0 + o) * cin + (ci0 + p)) * 9 + k];
            }
            wreg[it] = v;
        }
        // ---- phase B: write registers to LDS -------------------------------
        #pragma unroll
        for (int it = 0; it < NIT; ++it) {
            int q = tid + it * 256;
            if (q < TITEMS) {
                int p   = q / 1156;
                int rem = q - p * 1156;
                int yy  = rem / 34;
                int xx  = rem - yy * 34;
                tile[p][yy][xx] = rbuf[it];
            }
        }
        #pragma unroll
        for (int it = 0; it < NWIT; ++it) {
            int q = tid + it * 256;
            if (q < WITEMS) {
                int o   = q / (CICH * 9);
                int rem = q - o * (CICH * 9);
                int p   = rem / 9;
                int k   = rem - p * 9;
                wsh[o][p][k] = wreg[it];
            }
        }
        __syncthreads();

        #pragma unroll
        for (int p = 0; p < CICH; p++) {
            // 4x4 input patch for this thread's 2x2 outputs (8x ds_read_b64)
            float v[4][4];
            #pragma unroll
            for (int rr = 0; rr < 4; rr++) {
                const float2 a = *reinterpret_cast<const float2*>(&tile[p][2 * ly + rr][2 * lx]);
                const float2 b = *reinterpret_cast<const float2*>(&tile[p][2 * ly + rr][2 * lx + 2]);
                v[rr][0] = a.x; v[rr][1] = a.y; v[rr][2] = b.x; v[rr][3] = b.y;
            }
            #pragma unroll
            for (int o = 0; o < COT; o++) {
                const float4 wA = *reinterpret_cast<const float4*>(&wsh[o][p][0]);
                const float4 wB = *reinterpret_cast<const float4*>(&wsh[o][p][4]);
                const float  w8 = wsh[o][p][8];
                #pragma unroll
                for (int rr = 0; rr < 2; rr++) {
                    #pragma unroll
                    for (int ss = 0; ss < 2; ss++) {
                        acc[o][rr][ss] += wA.x * v[rr    ][ss] + wA.y * v[rr    ][ss + 1] + wA.z * v[rr    ][ss + 2]
                                        + wA.w * v[rr + 1][ss] + wB.x * v[rr + 1][ss + 1] + wB.y * v[rr + 1][ss + 2]
                                        + wB.z * v[rr + 2][ss] + wB.w * v[rr + 2][ss + 1] + w8   * v[rr + 2][ss + 2];
                    }
                }
            }
        }
        __syncthreads();
    }

    if (doFinal) {
        #pragma unroll
        for (int o = 0; o < COT; o++) {
            float b = bias[oc0 + o];
            #pragma unroll
            for (int rr = 0; rr < 2; rr++) {
                #pragma unroll
                for (int ss = 0; ss < 2; ss++) {
                    int oy2 = py0 + rr, ox2 = px0 + ss;
                    if (oy2 >= H2 || ox2 >= W2) continue;
                    float v = acc[o][rr][ss] + b;
                    if (doSilu) v = v / (1.f + __expf(-v));
                    if (toMask) {
                        int S = 2 << shift;   // 16 at stage 3
                        out[(long long)batch * 1024 * 1024 + (long long)(t * S + oy2) * 1024 + (l * S + ox2)] = v;
                    } else {
                        out[(long long)zb * outBatchStride + (long long)(oc0 + o) * oplane
                            + (long long)oy2 * outPitch + ox2] = v;
                    }
                }
            }
        }
    } else {
        // partial sum -> accumulator (bias/silu deferred to finalize_kernel)
        #pragma unroll
        for (int o = 0; o < COT; o++) {
            #pragma unroll
            for (int rr = 0; rr < 2; rr++) {
                #pragma unroll
                for (int ss = 0; ss < 2; ss++) {
                    int oy2 = py0 + rr, ox2 = px0 + ss;
                    if (oy2 >= H2 || ox2 >= W2) continue;
                    atomicAdd(&out[(long long)zb * outBatchStride + (long long)(oc0 + o) * oplane
                                   + (long long)oy2 * outPitch + ox2], acc[o][rr][ss]);
                }
            }
        }
    }
}

// ---------------------------------------------------------------------------
static inline void launch_conv(int co, int tiles32, int nz, int S,
                               const float* inB, long long inBS, int inPitch,
                               const float* wts, const float* bias, int cin, int doSilu,
                               float* out, long long outBS, int outPitch,
                               int toMask, int shift, const int* bboxes, int batch0,
                               hipStream_t stream)
{
    dim3 blk(16, 16);
    int bShift = (nz == 4) ? 2 : 0;
    int ciPer = cin / S;
    int doFinal = (S == 1) ? 1 : 0;
    dim3 grid;
    if (co == 64)      grid = dim3(tiles32, tiles32 * 8, nz * S);   // 8 groups of 8
    else if (co == 16) grid = dim3(tiles32, tiles32 * 2, nz * S);   // 2 groups of 8
    else               grid = dim3(tiles32, tiles32,     nz * S);   // 1 group (4 or 1)

    if (co == 64 || co == 16) {
        conv_reg_kernel<8><<<grid, blk, 0, stream>>>(
            inB, inBS, inPitch, wts, bias, cin, ciPer, bShift, doSilu,
            out, outBS, outPitch, toMask, doFinal, shift, bboxes, batch0, tiles32);
    } else if (co == 4) {
        conv_reg_kernel<4><<<grid, blk, 0, stream>>>(
            inB, inBS, inPitch, wts, bias, cin, ciPer, bShift, doSilu,
            out, outBS, outPitch, toMask, doFinal, shift, bboxes, batch0, tiles32);
    } else {
        conv_reg_kernel<1><<<grid, blk, 0, stream>>>(
            inB, inBS, inPitch, wts, bias, cin, ciPer, bShift, doSilu,
            out, outBS, outPitch, toMask, doFinal, shift, bboxes, batch0, tiles32);
    }
}

extern "C" void kernel_launch(void* const* d_in, const int* in_sizes, int n_in,
                              void* d_out, int out_size, void* d_ws, size_t ws_size,
                              hipStream_t stream)
{
    const float* x  = (const float*)d_in[0];
    const float* em[4];
    const float* gw[4];
    const float* gb[4];
    const float* cw[4];
    const float* cb[4];
    for (int j = 0; j < 4; j++) {
        em[j] = (const float*)d_in[1 + j];
        gw[j] = (const float*)d_in[5 + 4 * j];
        gb[j] = (const float*)d_in[6 + 4 * j];
        cw[j] = (const float*)d_in[7 + 4 * j];
        cb[j] = (const float*)d_in[8 + 4 * j];
    }
    const int* bboxes = (const int*)d_in[21];
    float* out = (float*)d_out;
    float* ws  = (float*)d_ws;

    const int chans[4] = {256, 64, 16, 4};
    const int couts[4] = {64, 16, 4, 1};
    const int splits[4] = {1, 1, 1, 1};     // cin-split OFF (R13: measured neutral)

    const long long A_OFF  = 256;
    const long long A_SLOT = 1048576;   // floats; co*up^2 == A_SLOT at every stage
    const long long B_SLOT = 4194304;   // floats: c_j * (128<<j)^2, same all stages

    bool par = ws_size >= (size_t)(A_OFF + 4 * A_SLOT + 4 * B_SLOT) * 4;
    int nA = par ? 4 : 1;
    float* accs = ws;
    float* bufA = ws + A_OFF;
    float* bufB = ws + A_OFF + nA * A_SLOT;

    // mask = -100 everywhere
    fill_kernel<<<(4194304 + 255) / 256, 256, 0, stream>>>(out, 4194304, -100.0f);

    if (par) {
        for (int j = 0; j < 4; j++) {
            int c = chans[j], co = couts[j], shift = j;
            int inPitch = 64 << j;
            long long inPlane = (long long)inPitch * inPitch;
            int upPitch = 128 << j;
            int tiles = upPitch / 16;
            int tiles32 = upPitch / 32;
            int E = 128 << j;
            long long emStride = (long long)c * E * E;
            int S = splits[j];

            const float* gin = (j == 0) ? x : bufA;
            long long ginStride = (j == 0) ? (long long)256 * 64 * 64 : A_SLOT;
            int useOrig = (j == 0) ? 1 : 0;

            zero8_kernel<<<1, 64, 0, stream>>>(accs);
            gn_reduce_kernel<<<dim3(512, 1, 4), 256, 0, stream>>>(
                gin, ginStride, inPitch, inPlane, useOrig, c, shift, bboxes, 0, accs);
            normup_kernel<<<dim3(tiles, tiles * c, 4), dim3(16, 16), 0, stream>>>(
                gin, ginStride, inPitch, inPlane, useOrig,
                em[j], emStride, E, gw[j], gb[j], accs,
                bufB, B_SLOT, upPitch, c, shift, bboxes, 0, tiles);
            if (S > 1) {
                fill_kernel<<<(int)((4 * A_SLOT + 255) / 256), 256, 0, stream>>>(
                    bufA, (int)(4 * A_SLOT), 0.f);
            }
            launch_conv(co, tiles32, 4, S,
                        bufB, B_SLOT, upPitch, cw[j], cb[j], c, (j < 3) ? 1 : 0,
                        (j < 3) ? bufA : out, (j < 3) ? A_SLOT : 0, upPitch,
                        (j == 3) ? 1 : 0, shift, bboxes, 0, stream);
            if (S > 1) {
                int ocShift = 2 * (7 + j);
                finalize_kernel<<<dim3(4096, 4), 256, 0, stream>>>(
                    bufA, A_SLOT, (int)A_SLOT, ocShift, cb[j], (j < 3) ? 1 : 0);
            }
        }
    } else {
        for (int i = 0; i < 4; i++) {
            for (int j = 0; j < 4; j++) {
                int c = chans[j], co = couts[j], shift = j;
                int inPitch = 64 << j;
                long long inPlane = (long long)inPitch * inPitch;
                int upPitch = 128 << j;
                int tiles = upPitch / 16;
                int tiles32 = upPitch / 32;
                int E = 128 << j;
                long long emStride = (long long)c * E * E;
                int S = splits[j];

                const float* gin = (j == 0) ? (x + (long long)i * 256 * 64 * 64) : bufA;
                int useOrig = (j == 0) ? 1 : 0;

                zero8_kernel<<<1, 64, 0, stream>>>(accs);
                gn_reduce_kernel<<<dim3(512, 1, 1), 256, 0, stream>>>(
                    gin, 0, inPitch, inPlane, useOrig, c, shift, bboxes, i, accs);
                normup_kernel<<<dim3(tiles, tiles * c, 1), dim3(16, 16), 0, stream>>>(
                    gin, 0, inPitch, inPlane, useOrig,
                    em[j] + (long long)i * emStride, 0, E, gw[j], gb[j], accs,
                    bufB, 0, upPitch, c, shift, bboxes, i, tiles);
                if (S > 1) {
                    fill_kernel<<<(int)((A_SLOT + 255) / 256), 256, 0, stream>>>(
                        bufA, (int)A_SLOT, 0.f);
                }
                launch_conv(co, tiles32, 1, S,
                            bufB, 0, upPitch, cw[j], cb[j], c, (j < 3) ? 1 : 0,
                            (j < 3) ? bufA : out, 0, upPitch,
                            (j == 3) ? 1 : 0, shift, bboxes, i, stream);
                if (S > 1) {
                    int ocShift = 2 * (7 + j);
                    finalize_kernel<<<dim3(4096, 1), 256, 0, stream>>>(
                        bufA, 0, (int)A_SLOT, ocShift, cb[j], (j < 3) ? 1 : 0);
                }
            }
        }
    }
}